// Round 7
// baseline (1588.981 us; speedup 1.0000x reference)
//
#include <hip/hip_runtime.h>
#include <hip/hip_bf16.h>

// SlicedLMHead: logits[2048][32000] = H[2048][4096] @ W[32000][4096]^T + bias
// Round 7: cvt W,H -> bf16 in d_ws; 256x256 GEMM with B (W) loaded DIRECTLY
// global->VGPR (no B in LDS). LDS holds A only (64 KB dbuf) -> CU LDS work
// (1911 cyc/tile) drops below MFMA (2483), removing the pipe that refused to
// overlap in rounds 3-6. A staged via global_load_lds + XOR swizzle; counted
// vmcnt(8) / lgkmcnt; 2 barriers/tile; 4 phases of 16 MFMA split (m-half,kk).

typedef __attribute__((ext_vector_type(8))) short bhalf8;   // 8 bf16
typedef __attribute__((ext_vector_type(4))) float f32x4;    // MFMA acc
typedef __attribute__((ext_vector_type(8))) unsigned short us8;

#define M_DIM 2048
#define N_DIM 32000
#define K_DIM 4096
#define BM 256
#define BN 256
#define BK 64
#define NT (K_DIM / BK)       // 64 K-tiles
#define MBLKS (M_DIM / BM)    // 8
#define NBLKS (N_DIM / BN)    // 125
#define NWG (MBLKS * NBLKS)   // 1000, divisible by 8

#define W_ELEMS ((size_t)N_DIM * K_DIM)
#define H_ELEMS ((size_t)M_DIM * K_DIM)
#define WS_NEEDED ((W_ELEMS + H_ELEMS) * 2)

#define GLOAD_LDS16(g, l) \
    __builtin_amdgcn_global_load_lds( \
        (const __attribute__((address_space(1))) unsigned int*)(g), \
        (__attribute__((address_space(3))) unsigned int*)(l), 16, 0, 0)

__device__ __forceinline__ unsigned short f2bf_rn(float f) {
    unsigned int u = __float_as_uint(f);
    u += 0x7FFFu + ((u >> 16) & 1u);
    return (unsigned short)(u >> 16);
}

// ---------------- fp32 -> bf16 conversion pass (memory-bound) ----------------
__global__ __launch_bounds__(256)
void cvt_f32_bf16(const float* __restrict__ in, unsigned short* __restrict__ out,
                  size_t n8) {
    size_t i = (size_t)blockIdx.x * blockDim.x + threadIdx.x;
    const size_t stride = (size_t)gridDim.x * blockDim.x;
    for (; i < n8; i += stride) {
        const float4 v0 = ((const float4*)in)[i * 2];
        const float4 v1 = ((const float4*)in)[i * 2 + 1];
        us8 p;
        p[0] = f2bf_rn(v0.x); p[1] = f2bf_rn(v0.y);
        p[2] = f2bf_rn(v0.z); p[3] = f2bf_rn(v0.w);
        p[4] = f2bf_rn(v1.x); p[5] = f2bf_rn(v1.y);
        p[6] = f2bf_rn(v1.z); p[7] = f2bf_rn(v1.w);
        ((us8*)out)[i] = p;
    }
}

// ---------------- 256^2 bf16 GEMM, B-direct-to-registers ----------------
// LDS (A only, elems): buf b, m-half h at (b*2+h)*8192. lds[row][g] holds
// global granule g ^ (row&7) (granule = 8 bf16 = 16 B).
// Per K-tile T (buf B = T&1), phases (16 MFMA each):
//  ph0: load bk1(T) [4 global]; lgkm(0) [af0 landed]; MFMA i0-3 x kk0 (BC0)
//  ph1: issue af1 reads (8 ds);                       MFMA i0-3 x kk1 (bk1)
//  ph2: load BN0=k0(T+1) [4 global]; lgkm(0) [af1];   MFMA i4-7 x kk0; BARRIER
//  ph3: stage A(T+2) [4 gload_lds]; vmcnt(8); BARRIER(publish);
//       issue af0'(T+1) reads (8 ds, buf B^1);        MFMA i4-7 x kk1
__global__ __launch_bounds__(512, 2)
void lmhead_gemm_bd(const unsigned short* __restrict__ A,  // [2048][4096] bf16
                    const unsigned short* __restrict__ W,  // [32000][4096] bf16
                    const float* __restrict__ bias,
                    float* __restrict__ C)
{
    __shared__ unsigned short lds[32768];  // 64 KB: A double-buffer only

    const int tid  = threadIdx.x;
    const int bid  = blockIdx.x;
    const int wgid = (bid & 7) * (NWG / 8) + (bid >> 3);  // bijective XCD chunks
    const int mblk = wgid & (MBLKS - 1);                  // M fastest-varying
    const int nblk = wgid >> 3;

    const int lane = tid & 63;
    const int wv   = tid >> 6;     // 0..7
    const int wr   = wv >> 2;      // 0..1 : wave M-half (128 rows)
    const int wc   = wv & 3;       // 0..3 : wave N-slot (64 cols)
    const int l15  = lane & 15;
    const int l4   = lane >> 4;

    // ---- A staging addressing ----
    const int strow = tid >> 3;                          // 0..63
    const int sgsw  = ((tid & 7) ^ (strow & 7)) << 3;    // pre-swizzled k-off
    const unsigned short* const srcA = A + (size_t)(mblk * BM + strow) * K_DIM + sgsw;
    const int dstw = (tid & 448) * 8;                    // wave-uniform LDS base

#define STAGE_A(u, h, BUF) { \
        const unsigned short* s_ = srcA + (size_t)((h) * 128) * K_DIM + (size_t)(u) * BK; \
        unsigned short* d_ = &lds[(((BUF) * 2 + (h)) * 8192) + dstw]; \
        GLOAD_LDS16(s_, d_); GLOAD_LDS16(s_ + (size_t)64 * K_DIM, d_ + 4096); }
#define STAGE_AT(u, BUF) { STAGE_A(u, 0, BUF); STAGE_A(u, 1, BUF); }

    // ---- A fragment read addressing (LDS) ----
    const int swz0 = (l4 ^ (l15 & 7)) << 3;          // kk=0 swizzled granule
    const int swz1 = ((4 + l4) ^ (l15 & 7)) << 3;    // kk=1
    const int arow = l15 * 64;

    // ---- B direct-load addressing (global): frag (j,kk) of tile T at
    //      bsrc[j] + T*64 + kk*32 (elems); 16 rows x 64 B segments ----
    const unsigned short* bsrc[4];
    #pragma unroll
    for (int j = 0; j < 4; ++j)
        bsrc[j] = W + (size_t)(nblk * BN + wc * 64 + j * 16 + l15) * K_DIM + l4 * 8;

    f32x4 acc[8][4] = {};
    bhalf8 af0[4][2], af1[4][2];      // A frags: m-half 0 / 1, both kk
    bhalf8 bX[4], bY[4], bk1[4];      // B k0 ping-pong + in-tile k1

#define BPF_K0(DST, T1) { \
        if ((T1) < NT) { \
            _Pragma("unroll") \
            for (int j = 0; j < 4; ++j) \
                DST[j] = *(const bhalf8*)(bsrc[j] + (size_t)(T1) * BK); } }
#define BPF_K1(T0) { \
        _Pragma("unroll") \
        for (int j = 0; j < 4; ++j) \
            bk1[j] = *(const bhalf8*)(bsrc[j] + (size_t)(T0) * BK + 32); }

#define ISSUE_AF0(BUF) { \
        const unsigned short* _as = &lds[((BUF) * 2 + wr) * 8192]; \
        _Pragma("unroll") \
        for (int i = 0; i < 4; ++i) { \
            af0[i][0] = *(const bhalf8*)&_as[arow + swz0 + i * 1024]; \
            af0[i][1] = *(const bhalf8*)&_as[arow + swz1 + i * 1024]; } }
#define ISSUE_AF1(BUF) { \
        const unsigned short* _as = &lds[((BUF) * 2 + wr) * 8192]; \
        _Pragma("unroll") \
        for (int i = 0; i < 4; ++i) { \
            af1[i][0] = *(const bhalf8*)&_as[arow + swz0 + 4096 + i * 1024]; \
            af1[i][1] = *(const bhalf8*)&_as[arow + swz1 + 4096 + i * 1024]; } }

#define MFMA16(AB, KK, BV, IOFF) { \
        _Pragma("unroll") \
        for (int i = 0; i < 4; ++i) \
            _Pragma("unroll") \
            for (int j = 0; j < 4; ++j) \
                acc[(IOFF) + i][j] = __builtin_amdgcn_mfma_f32_16x16x32_bf16( \
                    AB[i][KK], BV[j], acc[(IOFF) + i][j], 0, 0, 0); }

    // ---- prologue: stage A(0)->buf0, A(1)->buf1; B k0(0); read af0(0) ----
    STAGE_AT(0, 0);
    STAGE_AT(1, 1);
    BPF_K0(bX, 0);
    asm volatile("s_waitcnt vmcnt(8)" ::: "memory");   // A(0) landed
    __builtin_amdgcn_sched_barrier(0);
    __builtin_amdgcn_s_barrier();
    ISSUE_AF0(0);

#define TILE_STEP(T, B, BC0, BN0) { \
        /* ph0 */ \
        BPF_K1(T); \
        __builtin_amdgcn_sched_barrier(0); \
        asm volatile("s_waitcnt lgkmcnt(0)" ::: "memory"); \
        __builtin_amdgcn_sched_barrier(0); \
        __builtin_amdgcn_s_setprio(1); \
        MFMA16(af0, 0, BC0, 0); \
        __builtin_amdgcn_s_setprio(0); \
        /* ph1 */ \
        ISSUE_AF1(B); \
        __builtin_amdgcn_sched_barrier(0); \
        __builtin_amdgcn_s_setprio(1); \
        MFMA16(af0, 1, bk1, 0); \
        __builtin_amdgcn_s_setprio(0); \
        /* ph2 */ \
        BPF_K0(BN0, (T) + 1); \
        __builtin_amdgcn_sched_barrier(0); \
        asm volatile("s_waitcnt lgkmcnt(0)" ::: "memory"); \
        __builtin_amdgcn_sched_barrier(0); \
        __builtin_amdgcn_s_setprio(1); \
        MFMA16(af1, 0, BC0, 4); \
        __builtin_amdgcn_s_setprio(0); \
        __builtin_amdgcn_sched_barrier(0); \
        __builtin_amdgcn_s_barrier();            /* all buf-B reads done */ \
        /* ph3 */ \
        if ((T) + 2 < NT) STAGE_AT((T) + 2, B); \
        __builtin_amdgcn_sched_barrier(0); \
        if ((T) + 1 < NT) { asm volatile("s_waitcnt vmcnt(8)" ::: "memory"); } \
        else              { asm volatile("s_waitcnt vmcnt(0)" ::: "memory"); } \
        __builtin_amdgcn_sched_barrier(0); \
        __builtin_amdgcn_s_barrier();            /* publish A(T+1) */ \
        if ((T) + 1 < NT) ISSUE_AF0(B ^ 1); \
        __builtin_amdgcn_sched_barrier(0); \
        __builtin_amdgcn_s_setprio(1); \
        MFMA16(af1, 1, bk1, 4); \
        __builtin_amdgcn_s_setprio(0); }

    #pragma unroll 1
    for (int t = 0; t < NT; t += 2) {
        TILE_STEP(t,     0, bX, bY);
        TILE_STEP(t + 1, 1, bY, bX);
    }

    // ---- epilogue: D map row=(lane>>4)*4+r, col=lane&15 ----
    const size_t crow0 = (size_t)(mblk * BM + wr * 128 + l4 * 4);
    const int    ccol0 = nblk * BN + wc * 64 + l15;
    #pragma unroll
    for (int j = 0; j < 4; ++j) {
        const float bv = bias[ccol0 + j * 16];
        #pragma unroll
        for (int i = 0; i < 8; ++i) {
            const size_t base = (crow0 + (size_t)i * 16) * N_DIM + ccol0 + j * 16;
            #pragma unroll
            for (int r = 0; r < 4; ++r)
                C[base + (size_t)r * N_DIM] = acc[i][j][r] + bv;
        }
    }
#undef STAGE_A
#undef STAGE_AT
#undef BPF_K0
#undef BPF_K1
#undef ISSUE_AF0
#undef ISSUE_AF1
#undef MFMA16
#undef TILE_STEP
}

// ---------------- fallback (fp32 inputs, reg-staged 128^2) ----------------
__global__ __launch_bounds__(256, 2)
void lmhead_gemm_f32(const float* __restrict__ A, const float* __restrict__ W,
                     const float* __restrict__ bias, float* __restrict__ C) {
    __shared__ unsigned short As[2][128 * 64];
    __shared__ unsigned short Bs[2][128 * 64];

    const int tid  = threadIdx.x;
    const int bid  = blockIdx.x;
    const int mblk = bid & 15;
    const int nblk = bid >> 4;
    const int st_row = tid >> 3;
    const int st_g   = tid & 7;
    const int lane = tid & 63;
    const int wv   = tid >> 6;
    const int wm   = (wv >> 1) << 6;
    const int wn   = (wv & 1) << 6;
    const int l15  = lane & 15;
    const int l4   = lane >> 4;

    const float* aptr = A + (size_t)(mblk * 128 + st_row) * K_DIM + st_g * 8;
    const float* bptr = W + (size_t)(nblk * 128 + st_row) * K_DIM + st_g * 8;

    f32x4 acc[4][4] = {};
    float4 ra[4][2], rb[4][2];

    #pragma unroll
    for (int s = 0; s < 4; ++s) {
        const float* ap = aptr + (size_t)(s * 32) * K_DIM;
        const float* bp = bptr + (size_t)(s * 32) * K_DIM;
        ra[s][0] = *(const float4*)(ap);   ra[s][1] = *(const float4*)(ap + 4);
        rb[s][0] = *(const float4*)(bp);   rb[s][1] = *(const float4*)(bp + 4);
    }
    #pragma unroll
    for (int s = 0; s < 4; ++s) {
        const int row = s * 32 + st_row;
        const int off = row * 64 + ((st_g ^ (row & 7)) << 3);
        us8 pa, pb;
        #pragma unroll
        for (int j = 0; j < 4; ++j) {
            pa[j] = f2bf_rn(((const float*)&ra[s][0])[j]);
            pa[j + 4] = f2bf_rn(((const float*)&ra[s][1])[j]);
            pb[j] = f2bf_rn(((const float*)&rb[s][0])[j]);
            pb[j + 4] = f2bf_rn(((const float*)&rb[s][1])[j]);
        }
        *(us8*)&As[0][off] = pa;  *(us8*)&Bs[0][off] = pb;
    }
    __syncthreads();

    for (int t = 0; t < 64; ++t) {
        const int cur = t & 1;
        const bool more = (t + 1) < 64;
        if (more) {
            const float* ap = aptr + (size_t)(t + 1) * 64;
            const float* bp = bptr + (size_t)(t + 1) * 64;
            #pragma unroll
            for (int s = 0; s < 4; ++s) {
                ra[s][0] = *(const float4*)(ap + (size_t)(s * 32) * K_DIM);
                ra[s][1] = *(const float4*)(ap + (size_t)(s * 32) * K_DIM + 4);
                rb[s][0] = *(const float4*)(bp + (size_t)(s * 32) * K_DIM);
                rb[s][1] = *(const float4*)(bp + (size_t)(s * 32) * K_DIM + 4);
            }
        }
        const unsigned short* as = As[cur];
        const unsigned short* bs = Bs[cur];
        #pragma unroll
        for (int kk = 0; kk < 2; ++kk) {
            bhalf8 af[4], bfv[4];
            #pragma unroll
            for (int mf = 0; mf < 4; ++mf) {
                const int row = wm + mf * 16 + l15;
                af[mf] = *(const bhalf8*)&as[row * 64 + ((((kk << 2) + l4) ^ (row & 7)) << 3)];
            }
            #pragma unroll
            for (int nf = 0; nf < 4; ++nf) {
                const int row = wn + nf * 16 + l15;
                bfv[nf] = *(const bhalf8*)&bs[row * 64 + ((((kk << 2) + l4) ^ (row & 7)) << 3)];
            }
            #pragma unroll
            for (int mf = 0; mf < 4; ++mf)
                #pragma unroll
                for (int nf = 0; nf < 4; ++nf)
                    acc[mf][nf] = __builtin_amdgcn_mfma_f32_16x16x32_bf16(
                        af[mf], bfv[nf], acc[mf][nf], 0, 0, 0);
        }
        if (more) {
            const int nbuf = cur ^ 1;
            #pragma unroll
            for (int s = 0; s < 4; ++s) {
                const int row = s * 32 + st_row;
                const int off = row * 64 + ((st_g ^ (row & 7)) << 3);
                us8 pa, pb;
                #pragma unroll
                for (int j = 0; j < 4; ++j) {
                    pa[j] = f2bf_rn(((const float*)&ra[s][0])[j]);
                    pa[j + 4] = f2bf_rn(((const float*)&ra[s][1])[j]);
                    pb[j] = f2bf_rn(((const float*)&rb[s][0])[j]);
                    pb[j + 4] = f2bf_rn(((const float*)&rb[s][1])[j]);
                }
                *(us8*)&As[nbuf][off] = pa;  *(us8*)&Bs[nbuf][off] = pb;
            }
        }
        __syncthreads();
    }

    const size_t crow0 = (size_t)(mblk * 128 + wm + l4 * 4);
    const int    ccol0 = nblk * 128 + wn + l15;
    #pragma unroll
    for (int nf = 0; nf < 4; ++nf) {
        const float bv = bias[ccol0 + nf * 16];
        #pragma unroll
        for (int mf = 0; mf < 4; ++mf) {
            const size_t base = (crow0 + (size_t)mf * 16) * N_DIM + ccol0 + nf * 16;
            #pragma unroll
            for (int r = 0; r < 4; ++r)
                C[base + (size_t)r * N_DIM] = acc[mf][nf][r] + bv;
        }
    }
}

extern "C" void kernel_launch(void* const* d_in, const int* in_sizes, int n_in,
                              void* d_out, int out_size, void* d_ws, size_t ws_size,
                              hipStream_t stream) {
    const float* h = (const float*)d_in[0];
    const float* w = (const float*)d_in[1];
    const float* b = (const float*)d_in[2];
    float* out = (float*)d_out;
    // split_num (d_in[3]) is a semantic no-op: K-slices sum to the full GEMM.

    if (ws_size >= WS_NEEDED) {
        unsigned short* wbf = (unsigned short*)d_ws;
        unsigned short* hbf = wbf + W_ELEMS;
        cvt_f32_bf16<<<2048, 256, 0, stream>>>(w, wbf, W_ELEMS / 8);
        cvt_f32_bf16<<<512, 256, 0, stream>>>(h, hbf, H_ELEMS / 8);
        lmhead_gemm_bd<<<NWG, 512, 0, stream>>>(hbf, wbf, b, out);
    } else {
        lmhead_gemm_f32<<<4000, 256, 0, stream>>>(h, w, b, out);
    }
}

// Round 8
// 745.505 us; speedup vs baseline: 2.1314x; 2.1314x over previous
//
#include <hip/hip_runtime.h>
#include <hip/hip_bf16.h>

// SlicedLMHead: logits[2048][32000] = H[2048][4096] @ W[32000][4096]^T + bias
// Round 8: cvt W -> bf16 in FRAGMENT-LINEAR layout (each wave-fragment 1KB
// contiguous) so B loads global->VGPR are fully coalesced; LDS holds A only
// (64KB dbuf). Quadrant order (m0k0)(m1k0)(m0k1)(m1k1) + kk-split frags keeps
// VGPR <= R5's proven budget (R7 spilled: WRITE 1.73GB scratch). 1 barrier &
// counted vmcnt{0,4,4}/lgkm{0,0} per tile; all reads issued under MFMA.

typedef __attribute__((ext_vector_type(8))) short bhalf8;   // 8 bf16
typedef __attribute__((ext_vector_type(4))) float f32x4;    // MFMA acc
typedef __attribute__((ext_vector_type(8))) unsigned short us8;

#define M_DIM 2048
#define N_DIM 32000
#define K_DIM 4096
#define BM 256
#define BN 256
#define BK 64
#define NT (K_DIM / BK)       // 64 K-tiles
#define MBLKS (M_DIM / BM)    // 8
#define NBLKS (N_DIM / BN)    // 125
#define NWG (MBLKS * NBLKS)   // 1000, divisible by 8

#define W_ELEMS ((size_t)N_DIM * K_DIM)
#define H_ELEMS ((size_t)M_DIM * K_DIM)
#define WS_NEEDED ((W_ELEMS + H_ELEMS) * 2)

#define GLOAD_LDS16(g, l) \
    __builtin_amdgcn_global_load_lds( \
        (const __attribute__((address_space(1))) unsigned int*)(g), \
        (__attribute__((address_space(3))) unsigned int*)(l), 16, 0, 0)

__device__ __forceinline__ unsigned short f2bf_rn(float f) {
    unsigned int u = __float_as_uint(f);
    u += 0x7FFFu + ((u >> 16) & 1u);
    return (unsigned short)(u >> 16);
}

// ---------------- H: plain fp32 -> bf16 (row-major) ----------------
__global__ __launch_bounds__(256)
void cvt_f32_bf16(const float* __restrict__ in, unsigned short* __restrict__ out,
                  size_t n8) {
    size_t i = (size_t)blockIdx.x * blockDim.x + threadIdx.x;
    const size_t stride = (size_t)gridDim.x * blockDim.x;
    for (; i < n8; i += stride) {
        const float4 v0 = ((const float4*)in)[i * 2];
        const float4 v1 = ((const float4*)in)[i * 2 + 1];
        us8 p;
        p[0] = f2bf_rn(v0.x); p[1] = f2bf_rn(v0.y);
        p[2] = f2bf_rn(v0.z); p[3] = f2bf_rn(v0.w);
        p[4] = f2bf_rn(v1.x); p[5] = f2bf_rn(v1.y);
        p[6] = f2bf_rn(v1.z); p[7] = f2bf_rn(v1.w);
        ((us8*)out)[i] = p;
    }
}

// ---------------- W: fp32 -> bf16 fragment-linear reorder ----------------
// chunk c = (((nb*4 + wc)*64 + t)*2 + kk)*4 + j  (256,000 chunks of 512 bf16).
// Wn[c*512 + l*8 + e] = bf16( W[nb*256+wc*64+j*16+(l&15)][t*64+kk*32+(l>>4)*8+e] )
__global__ __launch_bounds__(256)
void cvt_w_frag(const float* __restrict__ w, unsigned short* __restrict__ wn) {
    const int lane  = threadIdx.x & 63;
    const int nwav  = gridDim.x * 4;
    const int l15   = lane & 15;
    const int l4g   = (lane >> 4) * 8;
    for (int c = blockIdx.x * 4 + (threadIdx.x >> 6); c < 256000; c += nwav) {
        const int j  = c & 3;
        const int kk = (c >> 2) & 1;
        const int t  = (c >> 3) & 63;
        const int wc = (c >> 9) & 3;
        const int nb = c >> 11;
        const int row = nb * 256 + wc * 64 + j * 16 + l15;
        const int k   = t * 64 + kk * 32 + l4g;
        const float* s = w + (size_t)row * K_DIM + k;
        const float4 v0 = *(const float4*)s;
        const float4 v1 = *(const float4*)(s + 4);
        us8 p;
        p[0] = f2bf_rn(v0.x); p[1] = f2bf_rn(v0.y);
        p[2] = f2bf_rn(v0.z); p[3] = f2bf_rn(v0.w);
        p[4] = f2bf_rn(v1.x); p[5] = f2bf_rn(v1.y);
        p[6] = f2bf_rn(v1.z); p[7] = f2bf_rn(v1.w);
        *(us8*)(wn + (size_t)c * 512 + lane * 8) = p;
    }
}

// ---------------- 256^2 bf16 GEMM, A-in-LDS + B-direct-coalesced ----------------
// LDS (A only): buf b, m-half h (128 rows) at (b*2+h)*8192 elems; lds[row][g]
// holds global granule g ^ (row&7). Quadrants: ph0 (m0,k0) ph1 (m1,k0)
// ph2 (m0,k1) ph3 (m1,k1). Per tile T (b=T&1):
//  ph0: vmcnt(0)[bgk0(T)]; lgkm(0)[afk0]; issue bgk1(T), stage A(T+1)->b^1,
//       afk1 reads; MFMA m0k0.  ph1: MFMA m1k0.
//  ph2: lgkm(0)[afk1]; vmcnt(4)[bgk1(T), A(T+1) stays]; issue bgk0(T+1);
//       MFMA m0k1.  ph3: MFMA m1k1; vmcnt(4)[A(T+1), bgk0(T+1) stays];
//       BARRIER; issue afk0(T+1) reads (buf b^1).
__global__ __launch_bounds__(512, 2)
void lmhead_gemm_bd2(const unsigned short* __restrict__ A,   // [2048][4096] bf16
                     const unsigned short* __restrict__ Wn,  // frag-linear bf16
                     const float* __restrict__ bias,
                     float* __restrict__ C)
{
    __shared__ unsigned short lds[32768];  // 64 KB: A double-buffer only

    const int tid  = threadIdx.x;
    const int bid  = blockIdx.x;
    const int wgid = (bid & 7) * (NWG / 8) + (bid >> 3);  // bijective XCD chunks
    const int mblk = wgid & (MBLKS - 1);                  // M fastest-varying
    const int nblk = wgid >> 3;

    const int lane = tid & 63;
    const int wv   = tid >> 6;     // 0..7
    const int wr   = wv >> 2;      // 0..1 : wave M-half (128 rows)
    const int wc   = wv & 3;       // 0..3 : wave N-slot (64 cols)
    const int l15  = lane & 15;
    const int l4   = lane >> 4;

    // ---- A staging addressing (proven R5/R7 scheme) ----
    const int strow = tid >> 3;                          // 0..63
    const int sgsw  = ((tid & 7) ^ (strow & 7)) << 3;    // pre-swizzled k-off
    const unsigned short* const srcA = A + (size_t)(mblk * BM + strow) * K_DIM + sgsw;
    const int dstw = (tid & 448) * 8;                    // wave-uniform LDS base

#define STAGE_A(u, h, BUF) { \
        const unsigned short* s_ = srcA + (size_t)((h) * 128) * K_DIM + (size_t)(u) * BK; \
        unsigned short* d_ = &lds[(((BUF) * 2 + (h)) * 8192) + dstw]; \
        GLOAD_LDS16(s_, d_); GLOAD_LDS16(s_ + (size_t)64 * K_DIM, d_ + 4096); }
#define STAGE_AT(u, BUF) { STAGE_A(u, 0, BUF); STAGE_A(u, 1, BUF); }

    // ---- A fragment reads (8 x ds_read_b128, one kk-half, both m-quarters) ----
    const int swz0 = (l4 ^ (l15 & 7)) << 3;
    const int swz1 = ((4 + l4) ^ (l15 & 7)) << 3;
    const int arow = l15 * 64;

#define ISSUE_AFK(DST, BUF, SWZ) { \
        const unsigned short* _as = &lds[((BUF) * 2 + wr) * 8192]; \
        _Pragma("unroll") \
        for (int i = 0; i < 8; ++i) \
            DST[i] = *(const bhalf8*)&_as[arow + (SWZ) + i * 1024]; }

    // ---- B direct coalesced loads: frag (t,kk,j) at wbase + ((t*2+kk)*4+j)*512 ----
    const unsigned short* const wbase =
        Wn + (size_t)(nblk * 4 + wc) * 262144 + lane * 8;

#define BLOADK(DST, T, KK) { \
        _Pragma("unroll") \
        for (int j = 0; j < 4; ++j) \
            DST[j] = *(const bhalf8*)(wbase + ((size_t)((T) * 2 + (KK)) * 4 + j) * 512); }

    f32x4 acc[8][4] = {};
    bhalf8 afk0[8], afk1[8];   // A frags kk=0 / kk=1 (both m-quarters)
    bhalf8 bgk0[4], bgk1[4];   // B frags kk=0 / kk=1

#define MFMA16Q(AF, BASE, BG) { \
        _Pragma("unroll") \
        for (int i = 0; i < 4; ++i) \
            _Pragma("unroll") \
            for (int j = 0; j < 4; ++j) \
                acc[(BASE) + i][j] = __builtin_amdgcn_mfma_f32_16x16x32_bf16( \
                    AF[(BASE) + i], BG[j], acc[(BASE) + i][j], 0, 0, 0); }

#define SBAR __builtin_amdgcn_sched_barrier(0)

    // ---- prologue: A(0)->buf0 [4], bgk0(0) [4]; drain A(0); read afk0 ----
    STAGE_AT(0, 0);
    SBAR;
    BLOADK(bgk0, 0, 0);
    SBAR;
    asm volatile("s_waitcnt vmcnt(4)" ::: "memory");   // A(0) landed; bgk0 flying
    SBAR;
    __builtin_amdgcn_s_barrier();
    ISSUE_AFK(afk0, 0, swz0);

    #pragma unroll 1
    for (int t = 0; t < NT; ++t) {
        const int b = t & 1;
        const bool more = (t + 1) < NT;

        // ===== ph0 =====
        asm volatile("s_waitcnt vmcnt(0)" ::: "memory");   // bgk0(t) landed
        SBAR;
        asm volatile("s_waitcnt lgkmcnt(0)" ::: "memory"); // afk0 landed
        SBAR;
        BLOADK(bgk1, t, 1);                                // [4]
        SBAR;
        if (more) STAGE_AT(t + 1, b ^ 1);                  // [4]
        SBAR;
        ISSUE_AFK(afk1, b, swz1);                          // 8 ds_read
        SBAR;
        __builtin_amdgcn_s_setprio(1);
        MFMA16Q(afk0, 0, bgk0);                            // (m0,k0)
        __builtin_amdgcn_s_setprio(0);
        // ===== ph1 =====
        __builtin_amdgcn_s_setprio(1);
        MFMA16Q(afk0, 4, bgk0);                            // (m1,k0)
        __builtin_amdgcn_s_setprio(0);
        SBAR;
        // ===== ph2 =====
        asm volatile("s_waitcnt lgkmcnt(0)" ::: "memory"); // afk1 landed
        SBAR;
        if (more) { asm volatile("s_waitcnt vmcnt(4)" ::: "memory"); }  // bgk1(t)
        else      { asm volatile("s_waitcnt vmcnt(0)" ::: "memory"); }
        SBAR;
        if (more) BLOADK(bgk0, t + 1, 0);                  // [4]
        SBAR;
        __builtin_amdgcn_s_setprio(1);
        MFMA16Q(afk1, 0, bgk1);                            // (m0,k1)
        __builtin_amdgcn_s_setprio(0);
        // ===== ph3 =====
        __builtin_amdgcn_s_setprio(1);
        MFMA16Q(afk1, 4, bgk1);                            // (m1,k1)
        __builtin_amdgcn_s_setprio(0);
        SBAR;
        if (more) { asm volatile("s_waitcnt vmcnt(4)" ::: "memory"); }  // A(t+1)
        else      { asm volatile("s_waitcnt vmcnt(0)" ::: "memory"); }
        SBAR;
        __builtin_amdgcn_s_barrier();                      // publish A(t+1)
        if (more) ISSUE_AFK(afk0, b ^ 1, swz0);
        SBAR;
    }

    // ---- epilogue: D map row=(lane>>4)*4+r, col=lane&15 ----
    const size_t crow0 = (size_t)(mblk * BM + wr * 128 + l4 * 4);
    const int    ccol0 = nblk * BN + wc * 64 + l15;
    #pragma unroll
    for (int j = 0; j < 4; ++j) {
        const float bv = bias[ccol0 + j * 16];
        #pragma unroll
        for (int i = 0; i < 8; ++i) {
            const size_t base = (crow0 + (size_t)i * 16) * N_DIM + ccol0 + j * 16;
            #pragma unroll
            for (int r = 0; r < 4; ++r)
                C[base + (size_t)r * N_DIM] = acc[i][j][r] + bv;
        }
    }
#undef STAGE_A
#undef STAGE_AT
#undef ISSUE_AFK
#undef BLOADK
#undef MFMA16Q
#undef SBAR
}

// ---------------- fallback (fp32 inputs, reg-staged 128^2) ----------------
__global__ __launch_bounds__(256, 2)
void lmhead_gemm_f32(const float* __restrict__ A, const float* __restrict__ W,
                     const float* __restrict__ bias, float* __restrict__ C) {
    __shared__ unsigned short As[2][128 * 64];
    __shared__ unsigned short Bs[2][128 * 64];

    const int tid  = threadIdx.x;
    const int bid  = blockIdx.x;
    const int mblk = bid & 15;
    const int nblk = bid >> 4;
    const int st_row = tid >> 3;
    const int st_g   = tid & 7;
    const int lane = tid & 63;
    const int wv   = tid >> 6;
    const int wm   = (wv >> 1) << 6;
    const int wn   = (wv & 1) << 6;
    const int l15  = lane & 15;
    const int l4   = lane >> 4;

    const float* aptr = A + (size_t)(mblk * 128 + st_row) * K_DIM + st_g * 8;
    const float* bptr = W + (size_t)(nblk * 128 + st_row) * K_DIM + st_g * 8;

    f32x4 acc[4][4] = {};
    float4 ra[4][2], rb[4][2];

    #pragma unroll
    for (int s = 0; s < 4; ++s) {
        const float* ap = aptr + (size_t)(s * 32) * K_DIM;
        const float* bp = bptr + (size_t)(s * 32) * K_DIM;
        ra[s][0] = *(const float4*)(ap);   ra[s][1] = *(const float4*)(ap + 4);
        rb[s][0] = *(const float4*)(bp);   rb[s][1] = *(const float4*)(bp + 4);
    }
    #pragma unroll
    for (int s = 0; s < 4; ++s) {
        const int row = s * 32 + st_row;
        const int off = row * 64 + ((st_g ^ (row & 7)) << 3);
        us8 pa, pb;
        #pragma unroll
        for (int j = 0; j < 4; ++j) {
            pa[j] = f2bf_rn(((const float*)&ra[s][0])[j]);
            pa[j + 4] = f2bf_rn(((const float*)&ra[s][1])[j]);
            pb[j] = f2bf_rn(((const float*)&rb[s][0])[j]);
            pb[j + 4] = f2bf_rn(((const float*)&rb[s][1])[j]);
        }
        *(us8*)&As[0][off] = pa;  *(us8*)&Bs[0][off] = pb;
    }
    __syncthreads();

    for (int t = 0; t < 64; ++t) {
        const int cur = t & 1;
        const bool more = (t + 1) < 64;
        if (more) {
            const float* ap = aptr + (size_t)(t + 1) * 64;
            const float* bp = bptr + (size_t)(t + 1) * 64;
            #pragma unroll
            for (int s = 0; s < 4; ++s) {
                ra[s][0] = *(const float4*)(ap + (size_t)(s * 32) * K_DIM);
                ra[s][1] = *(const float4*)(ap + (size_t)(s * 32) * K_DIM + 4);
                rb[s][0] = *(const float4*)(bp + (size_t)(s * 32) * K_DIM);
                rb[s][1] = *(const float4*)(bp + (size_t)(s * 32) * K_DIM + 4);
            }
        }
        const unsigned short* as = As[cur];
        const unsigned short* bs = Bs[cur];
        #pragma unroll
        for (int kk = 0; kk < 2; ++kk) {
            bhalf8 af[4], bfv[4];
            #pragma unroll
            for (int mf = 0; mf < 4; ++mf) {
                const int row = wm + mf * 16 + l15;
                af[mf] = *(const bhalf8*)&as[row * 64 + ((((kk << 2) + l4) ^ (row & 7)) << 3)];
            }
            #pragma unroll
            for (int nf = 0; nf < 4; ++nf) {
                const int row = wn + nf * 16 + l15;
                bfv[nf] = *(const bhalf8*)&bs[row * 64 + ((((kk << 2) + l4) ^ (row & 7)) << 3)];
            }
            #pragma unroll
            for (int mf = 0; mf < 4; ++mf)
                #pragma unroll
                for (int nf = 0; nf < 4; ++nf)
                    acc[mf][nf] = __builtin_amdgcn_mfma_f32_16x16x32_bf16(
                        af[mf], bfv[nf], acc[mf][nf], 0, 0, 0);
        }
        if (more) {
            const int nbuf = cur ^ 1;
            #pragma unroll
            for (int s = 0; s < 4; ++s) {
                const int row = s * 32 + st_row;
                const int off = row * 64 + ((st_g ^ (row & 7)) << 3);
                us8 pa, pb;
                #pragma unroll
                for (int j = 0; j < 4; ++j) {
                    pa[j] = f2bf_rn(((const float*)&ra[s][0])[j]);
                    pa[j + 4] = f2bf_rn(((const float*)&ra[s][1])[j]);
                    pb[j] = f2bf_rn(((const float*)&rb[s][0])[j]);
                    pb[j + 4] = f2bf_rn(((const float*)&rb[s][1])[j]);
                }
                *(us8*)&As[nbuf][off] = pa;  *(us8*)&Bs[nbuf][off] = pb;
            }
        }
        __syncthreads();
    }

    const size_t crow0 = (size_t)(mblk * 128 + wm + l4 * 4);
    const int    ccol0 = nblk * 128 + wn + l15;
    #pragma unroll
    for (int nf = 0; nf < 4; ++nf) {
        const float bv = bias[ccol0 + nf * 16];
        #pragma unroll
        for (int mf = 0; mf < 4; ++mf) {
            const size_t base = (crow0 + (size_t)mf * 16) * N_DIM + ccol0 + nf * 16;
            #pragma unroll
            for (int r = 0; r < 4; ++r)
                C[base + (size_t)r * N_DIM] = acc[mf][nf][r] + bv;
        }
    }
}

extern "C" void kernel_launch(void* const* d_in, const int* in_sizes, int n_in,
                              void* d_out, int out_size, void* d_ws, size_t ws_size,
                              hipStream_t stream) {
    const float* h = (const float*)d_in[0];
    const float* w = (const float*)d_in[1];
    const float* b = (const float*)d_in[2];
    float* out = (float*)d_out;
    // split_num (d_in[3]) is a semantic no-op: K-slices sum to the full GEMM.

    if (ws_size >= WS_NEEDED) {
        unsigned short* wbf = (unsigned short*)d_ws;       // fragment-linear W
        unsigned short* hbf = wbf + W_ELEMS;               // row-major H
        cvt_w_frag<<<2048, 256, 0, stream>>>(w, wbf);
        cvt_f32_bf16<<<512, 256, 0, stream>>>(h, hbf, H_ELEMS / 8);
        lmhead_gemm_bd2<<<NWG, 512, 0, stream>>>(hbf, wbf, b, out);
    } else {
        lmhead_gemm_f32<<<4000, 256, 0, stream>>>(h, w, b, out);
    }
}

// Round 10
// 622.277 us; speedup vs baseline: 2.5535x; 1.1980x over previous
//
#include <hip/hip_runtime.h>
#include <hip/hip_bf16.h>

// SlicedLMHead: logits[2048][32000] = H[2048][4096] @ W[32000][4096]^T + bias
// Round 10: R9's 8-phase / 2-tile rhythm with the sync bug FIXED: the counted
// vmcnt drain is placed BEFORE the closing barrier of ph3/ph7 (drain-own ->
// barrier -> read), so cross-wave LDS staging is published before any wave
// reads it. vmcnt(2) mid-loop (never 0); lgkm(4/8/0) counted; 1 half-tile
// staged per phase; reads issued a full phase ahead under MFMA clusters.

typedef __attribute__((ext_vector_type(8))) short bhalf8;   // 8 bf16
typedef __attribute__((ext_vector_type(4))) float f32x4;    // MFMA acc
typedef __attribute__((ext_vector_type(8))) unsigned short us8;

#define M_DIM 2048
#define N_DIM 32000
#define K_DIM 4096
#define BM 256
#define BN 256
#define BK 64
#define NT (K_DIM / BK)       // 64 K-tiles
#define MBLKS (M_DIM / BM)    // 8
#define NBLKS (N_DIM / BN)    // 125
#define NWG (MBLKS * NBLKS)   // 1000, divisible by 8

#define W_ELEMS ((size_t)N_DIM * K_DIM)
#define H_ELEMS ((size_t)M_DIM * K_DIM)
#define WS_NEEDED ((W_ELEMS + H_ELEMS) * 2)

#define GLOAD_LDS16(g, l) \
    __builtin_amdgcn_global_load_lds( \
        (const __attribute__((address_space(1))) unsigned int*)(g), \
        (__attribute__((address_space(3))) unsigned int*)(l), 16, 0, 0)

__device__ __forceinline__ unsigned short f2bf_rn(float f) {
    unsigned int u = __float_as_uint(f);
    u += 0x7FFFu + ((u >> 16) & 1u);
    return (unsigned short)(u >> 16);
}

// ---------------- fp32 -> bf16 conversion pass (memory-bound) ----------------
__global__ __launch_bounds__(256)
void cvt_f32_bf16(const float* __restrict__ in, unsigned short* __restrict__ out,
                  size_t n8) {
    size_t i = (size_t)blockIdx.x * blockDim.x + threadIdx.x;
    const size_t stride = (size_t)gridDim.x * blockDim.x;
    for (; i < n8; i += stride) {
        const float4 v0 = ((const float4*)in)[i * 2];
        const float4 v1 = ((const float4*)in)[i * 2 + 1];
        us8 p;
        p[0] = f2bf_rn(v0.x); p[1] = f2bf_rn(v0.y);
        p[2] = f2bf_rn(v0.z); p[3] = f2bf_rn(v0.w);
        p[4] = f2bf_rn(v1.x); p[5] = f2bf_rn(v1.y);
        p[6] = f2bf_rn(v1.z); p[7] = f2bf_rn(v1.w);
        ((us8*)out)[i] = p;
    }
}

// ---------------- 256^2 bf16 GEMM, 8-phase / 2-tile, fixed ledger ----------------
// LDS (elems): A half (buf,h) at (buf*2+h)*8192; B half at 32768+(buf*2+h)*8192.
// lds[row][g] holds global granule g ^ (row&7) (granule = 8 bf16 = 16 B).
// Iter s2: T0=s2 (buf0), T1=s2+1 (buf1). Stages (1 half-tile/phase):
//  ph1: b1.A.h0<-T1   ph2: b1.A.h1<-T1   ph3: b0.B.h0<-T0+2  ph4: b0.B.h1<-T0+2
//  ph5: b0.A.h0<-T0+2 ph6: b0.A.h1<-T0+2 ph7: b1.B.h0<-T1+2  ph8: b1.B.h1<-T1+2
// Drains: VMC(2) at END of ph3 (before barrier; 8 oldest = all of buf1/T1) and
// END of ph7 (8 oldest = all of buf0/T0+2). Reads: ph1 bf23(4), ph2 af1(8),
// ph4 af0+bf01 of T1 (12, post-publish), ph5 bf23(4), ph6 af1(8), ph8 af0+bf01
// of T0+2 (12). lgkm: ph1(4) ph2(8) ph3(0) ph5(4) ph6(8) ph7(0).
__global__ __launch_bounds__(512, 2)
void lmhead_gemm_256(const unsigned short* __restrict__ A,  // [2048][4096] bf16
                     const unsigned short* __restrict__ W,  // [32000][4096] bf16
                     const float* __restrict__ bias,
                     float* __restrict__ C)
{
    __shared__ unsigned short lds[65536];  // 128 KB

    const int tid  = threadIdx.x;
    const int bid  = blockIdx.x;
    const int wgid = (bid & 7) * (NWG / 8) + (bid >> 3);  // bijective XCD chunks
    const int mblk = wgid & (MBLKS - 1);                  // M fastest-varying
    const int nblk = wgid >> 3;

    const int lane = tid & 63;
    const int wv   = tid >> 6;     // 0..7
    const int wr   = wv >> 2;      // 0..1 : wave M-half (128 rows)
    const int wc   = wv & 3;       // 0..3 : wave N-slot (64 cols)
    const int l15  = lane & 15;
    const int l4   = lane >> 4;

    // ---- staging addressing ----
    const int strow = tid >> 3;                          // 0..63
    const int sgsw  = ((tid & 7) ^ (strow & 7)) << 3;    // pre-swizzled k-off
    const unsigned short* const srcA = A + (size_t)(mblk * BM + strow) * K_DIM + sgsw;
    const unsigned short* const srcB = W + (size_t)(nblk * BN + strow) * K_DIM + sgsw;
    const int dstw = (tid & 448) * 8;                    // wave-uniform LDS base

#define STAGE_A(u, h, BUF) { \
        const unsigned short* s_ = srcA + (size_t)((h) * 128) * K_DIM + (size_t)(u) * BK; \
        unsigned short* d_ = &lds[(((BUF) * 2 + (h)) * 8192) + dstw]; \
        GLOAD_LDS16(s_, d_); GLOAD_LDS16(s_ + (size_t)64 * K_DIM, d_ + 4096); }
#define STAGE_B(u, h, BUF) { \
        const unsigned short* s_ = srcB + (size_t)((h) * 128) * K_DIM + (size_t)(u) * BK; \
        unsigned short* d_ = &lds[32768 + (((BUF) * 2 + (h)) * 8192) + dstw]; \
        GLOAD_LDS16(s_, d_); GLOAD_LDS16(s_ + (size_t)64 * K_DIM, d_ + 4096); }

    // ---- fragment read addressing ----
    const int swz0 = (l4 ^ (l15 & 7)) << 3;          // kk=0 swizzled granule
    const int swz1 = ((4 + l4) ^ (l15 & 7)) << 3;    // kk=1
    const int arow = l15 * 64;
    const int brow = ((wc & 1) * 64 + l15) * 64;

    f32x4 acc[8][4] = {};
    bhalf8 af0[4][2], af1[4][2], bf01[2][2], bf23[2][2];

#define READ_AF0(BUF) { \
        const unsigned short* _as = &lds[((BUF) * 2 + wr) * 8192]; \
        _Pragma("unroll") \
        for (int i = 0; i < 4; ++i) { \
            af0[i][0] = *(const bhalf8*)&_as[arow + swz0 + i * 1024]; \
            af0[i][1] = *(const bhalf8*)&_as[arow + swz1 + i * 1024]; } }
#define READ_AF1(BUF) { \
        const unsigned short* _as = &lds[((BUF) * 2 + wr) * 8192]; \
        _Pragma("unroll") \
        for (int i = 0; i < 4; ++i) { \
            af1[i][0] = *(const bhalf8*)&_as[arow + swz0 + 4096 + i * 1024]; \
            af1[i][1] = *(const bhalf8*)&_as[arow + swz1 + 4096 + i * 1024]; } }
#define READ_BF01(BUF) { \
        const unsigned short* _bs = &lds[32768 + ((BUF) * 2 + (wc >> 1)) * 8192]; \
        _Pragma("unroll") \
        for (int j = 0; j < 2; ++j) { \
            bf01[j][0] = *(const bhalf8*)&_bs[brow + swz0 + j * 1024]; \
            bf01[j][1] = *(const bhalf8*)&_bs[brow + swz1 + j * 1024]; } }
#define READ_BF23(BUF) { \
        const unsigned short* _bs = &lds[32768 + ((BUF) * 2 + (wc >> 1)) * 8192]; \
        _Pragma("unroll") \
        for (int j = 0; j < 2; ++j) { \
            bf23[j][0] = *(const bhalf8*)&_bs[brow + swz0 + (2 + j) * 1024]; \
            bf23[j][1] = *(const bhalf8*)&_bs[brow + swz1 + (2 + j) * 1024]; } }

#define MFMA8Q(AF, BF, IOFF, JOFF) { \
        _Pragma("unroll") \
        for (int i = 0; i < 4; ++i) \
            _Pragma("unroll") \
            for (int j = 0; j < 2; ++j) \
                _Pragma("unroll") \
                for (int kk = 0; kk < 2; ++kk) \
                    acc[(IOFF) + i][(JOFF) + j] = __builtin_amdgcn_mfma_f32_16x16x32_bf16( \
                        AF[i][kk], BF[j][kk], acc[(IOFF) + i][(JOFF) + j], 0, 0, 0); }

#define SBAR  __builtin_amdgcn_sched_barrier(0)
#define BARR  __builtin_amdgcn_s_barrier()
#define LGKM(n) asm volatile("s_waitcnt lgkmcnt(" #n ")" ::: "memory")
#define VMC(n)  asm volatile("s_waitcnt vmcnt(" #n ")" ::: "memory")
#define PRIO1 __builtin_amdgcn_s_setprio(1)
#define PRIO0 __builtin_amdgcn_s_setprio(0)

    // ---- prologue: tile0 (buf0 A+B) + tile1 B (buf1) = 12 loads ----
    STAGE_A(0, 0, 0); STAGE_A(0, 1, 0);
    STAGE_B(0, 0, 0); STAGE_B(0, 1, 0);
    STAGE_B(1, 0, 1); STAGE_B(1, 1, 1);
    SBAR;
    VMC(4);                      // drain own tile0 loads BEFORE barrier
    SBAR;
    BARR;                        // tile0 published everywhere
    READ_AF0(0); READ_BF01(0);   // 12 reads for ph1's MFMA
    SBAR;

    #pragma unroll 1
    for (int s2 = 0; s2 < NT; s2 += 2) {
        const int T1 = s2 + 1;
        const bool m2 = (s2 + 2) < NT;

        // ===== ph1: read bf23(b0); stage b1.A.h0<-T1; q00(T0) =====
        READ_BF23(0); STAGE_A(T1, 0, 1); SBAR;
        BARR; LGKM(4); SBAR;
        PRIO1; MFMA8Q(af0, bf01, 0, 0); PRIO0; SBAR;
        BARR;
        // ===== ph2: read af1(b0); stage b1.A.h1<-T1; q01(T0) =====
        READ_AF1(0); STAGE_A(T1, 1, 1); SBAR;
        BARR; LGKM(8); SBAR;
        PRIO1; MFMA8Q(af0, bf23, 0, 2); PRIO0; SBAR;
        BARR;
        // ===== ph3: stage b0.B.h0<-T0+2; q10(T0); DRAIN buf1 BEFORE barrier =====
        if (m2) STAGE_B(s2 + 2, 0, 0);
        SBAR;
        BARR; LGKM(0); SBAR;
        PRIO1; MFMA8Q(af1, bf01, 4, 0); PRIO0; SBAR;
        if (m2) { VMC(2); } else { VMC(0); }   // buf1 (T1) fully landed, own part
        SBAR;
        BARR;                                  // buf1 published everywhere
        // ===== ph4: read af0+bf01 (b1,T1); stage b0.B.h1<-T0+2; q11(T0) =====
        READ_AF0(1); READ_BF01(1);
        if (m2) STAGE_B(s2 + 2, 1, 0);
        SBAR;
        BARR; SBAR;                            // no lgkm: af1/bf23 landed at ph3
        PRIO1; MFMA8Q(af1, bf23, 4, 2); PRIO0; SBAR;
        BARR;
        // ===== ph5: read bf23(b1); stage b0.A.h0<-T0+2; q00(T1) =====
        READ_BF23(1);
        if (m2) STAGE_A(s2 + 2, 0, 0);
        SBAR;
        BARR; LGKM(4); SBAR;
        PRIO1; MFMA8Q(af0, bf01, 0, 0); PRIO0; SBAR;
        BARR;
        // ===== ph6: read af1(b1); stage b0.A.h1<-T0+2; q01(T1) =====
        READ_AF1(1);
        if (m2) STAGE_A(s2 + 2, 1, 0);
        SBAR;
        BARR; LGKM(8); SBAR;
        PRIO1; MFMA8Q(af0, bf23, 0, 2); PRIO0; SBAR;
        BARR;
        // ===== ph7: stage b1.B.h0<-T1+2; q10(T1); DRAIN buf0 BEFORE barrier =====
        if (m2) STAGE_B(T1 + 2, 0, 1);
        SBAR;
        BARR; LGKM(0); SBAR;
        PRIO1; MFMA8Q(af1, bf01, 4, 0); PRIO0; SBAR;
        if (m2) { VMC(2); } else { VMC(0); }   // buf0 (T0+2) fully landed, own part
        SBAR;
        BARR;                                  // buf0 published everywhere
        // ===== ph8: read af0+bf01 (b0,T0+2); stage b1.B.h1<-T1+2; q11(T1) =====
        if (m2) { READ_AF0(0); READ_BF01(0); }
        if (m2) STAGE_B(T1 + 2, 1, 1);
        SBAR;
        BARR; SBAR;                            // no lgkm: af1/bf23 landed at ph7
        PRIO1; MFMA8Q(af1, bf23, 4, 2); PRIO0; SBAR;
        BARR;
    }

    // ---- epilogue: D map row=(lane>>4)*4+r, col=lane&15 ----
    const size_t crow0 = (size_t)(mblk * BM + wr * 128 + l4 * 4);
    const int    ccol0 = nblk * BN + wc * 64 + l15;
    #pragma unroll
    for (int j = 0; j < 4; ++j) {
        const float bv = bias[ccol0 + j * 16];
        #pragma unroll
        for (int i = 0; i < 8; ++i) {
            const size_t base = (crow0 + (size_t)i * 16) * N_DIM + ccol0 + j * 16;
            #pragma unroll
            for (int r = 0; r < 4; ++r)
                C[base + (size_t)r * N_DIM] = acc[i][j][r] + bv;
        }
    }
#undef STAGE_A
#undef STAGE_B
#undef READ_AF0
#undef READ_AF1
#undef READ_BF01
#undef READ_BF23
#undef MFMA8Q
#undef SBAR
#undef BARR
#undef LGKM
#undef VMC
#undef PRIO1
#undef PRIO0
}

// ---------------- fallback (fp32 inputs, reg-staged 128^2) ----------------
__global__ __launch_bounds__(256, 2)
void lmhead_gemm_f32(const float* __restrict__ A, const float* __restrict__ W,
                     const float* __restrict__ bias, float* __restrict__ C) {
    __shared__ unsigned short As[2][128 * 64];
    __shared__ unsigned short Bs[2][128 * 64];

    const int tid  = threadIdx.x;
    const int bid  = blockIdx.x;
    const int mblk = bid & 15;
    const int nblk = bid >> 4;
    const int st_row = tid >> 3;
    const int st_g   = tid & 7;
    const int lane = tid & 63;
    const int wv   = tid >> 6;
    const int wm   = (wv >> 1) << 6;
    const int wn   = (wv & 1) << 6;
    const int l15  = lane & 15;
    const int l4   = lane >> 4;

    const float* aptr = A + (size_t)(mblk * 128 + st_row) * K_DIM + st_g * 8;
    const float* bptr = W + (size_t)(nblk * 128 + st_row) * K_DIM + st_g * 8;

    f32x4 acc[4][4] = {};
    float4 ra[4][2], rb[4][2];

    #pragma unroll
    for (int s = 0; s < 4; ++s) {
        const float* ap = aptr + (size_t)(s * 32) * K_DIM;
        const float* bp = bptr + (size_t)(s * 32) * K_DIM;
        ra[s][0] = *(const float4*)(ap);   ra[s][1] = *(const float4*)(ap + 4);
        rb[s][0] = *(const float4*)(bp);   rb[s][1] = *(const float4*)(bp + 4);
    }
    #pragma unroll
    for (int s = 0; s < 4; ++s) {
        const int row = s * 32 + st_row;
        const int off = row * 64 + ((st_g ^ (row & 7)) << 3);
        us8 pa, pb;
        #pragma unroll
        for (int j = 0; j < 4; ++j) {
            pa[j] = f2bf_rn(((const float*)&ra[s][0])[j]);
            pa[j + 4] = f2bf_rn(((const float*)&ra[s][1])[j]);
            pb[j] = f2bf_rn(((const float*)&rb[s][0])[j]);
            pb[j + 4] = f2bf_rn(((const float*)&rb[s][1])[j]);
        }
        *(us8*)&As[0][off] = pa;  *(us8*)&Bs[0][off] = pb;
    }
    __syncthreads();

    for (int t = 0; t < 64; ++t) {
        const int cur = t & 1;
        const bool more = (t + 1) < 64;
        if (more) {
            const float* ap = aptr + (size_t)(t + 1) * 64;
            const float* bp = bptr + (size_t)(t + 1) * 64;
            #pragma unroll
            for (int s = 0; s < 4; ++s) {
                ra[s][0] = *(const float4*)(ap + (size_t)(s * 32) * K_DIM);
                ra[s][1] = *(const float4*)(ap + (size_t)(s * 32) * K_DIM + 4);
                rb[s][0] = *(const float4*)(bp + (size_t)(s * 32) * K_DIM);
                rb[s][1] = *(const float4*)(bp + (size_t)(s * 32) * K_DIM + 4);
            }
        }
        const unsigned short* as = As[cur];
        const unsigned short* bs = Bs[cur];
        #pragma unroll
        for (int kk = 0; kk < 2; ++kk) {
            bhalf8 af[4], bfv[4];
            #pragma unroll
            for (int mf = 0; mf < 4; ++mf) {
                const int row = wm + mf * 16 + l15;
                af[mf] = *(const bhalf8*)&as[row * 64 + ((((kk << 2) + l4) ^ (row & 7)) << 3)];
            }
            #pragma unroll
            for (int nf = 0; nf < 4; ++nf) {
                const int row = wn + nf * 16 + l15;
                bfv[nf] = *(const bhalf8*)&bs[row * 64 + ((((kk << 2) + l4) ^ (row & 7)) << 3)];
            }
            #pragma unroll
            for (int mf = 0; mf < 4; ++mf)
                #pragma unroll
                for (int nf = 0; nf < 4; ++nf)
                    acc[mf][nf] = __builtin_amdgcn_mfma_f32_16x16x32_bf16(
                        af[mf], bfv[nf], acc[mf][nf], 0, 0, 0);
        }
        if (more) {
            const int nbuf = cur ^ 1;
            #pragma unroll
            for (int s = 0; s < 4; ++s) {
                const int row = s * 32 + st_row;
                const int off = row * 64 + ((st_g ^ (row & 7)) << 3);
                us8 pa, pb;
                #pragma unroll
                for (int j = 0; j < 4; ++j) {
                    pa[j] = f2bf_rn(((const float*)&ra[s][0])[j]);
                    pa[j + 4] = f2bf_rn(((const float*)&ra[s][1])[j]);
                    pb[j] = f2bf_rn(((const float*)&rb[s][0])[j]);
                    pb[j + 4] = f2bf_rn(((const float*)&rb[s][1])[j]);
                }
                *(us8*)&As[nbuf][off] = pa;  *(us8*)&Bs[nbuf][off] = pb;
            }
        }
        __syncthreads();
    }

    const size_t crow0 = (size_t)(mblk * 128 + wm + l4 * 4);
    const int    ccol0 = nblk * 128 + wn + l15;
    #pragma unroll
    for (int nf = 0; nf < 4; ++nf) {
        const float bv = bias[ccol0 + nf * 16];
        #pragma unroll
        for (int mf = 0; mf < 4; ++mf) {
            const size_t base = (crow0 + (size_t)mf * 16) * N_DIM + ccol0 + nf * 16;
            #pragma unroll
            for (int r = 0; r < 4; ++r)
                C[base + (size_t)r * N_DIM] = acc[mf][nf][r] + bv;
        }
    }
}

extern "C" void kernel_launch(void* const* d_in, const int* in_sizes, int n_in,
                              void* d_out, int out_size, void* d_ws, size_t ws_size,
                              hipStream_t stream) {
    const float* h = (const float*)d_in[0];
    const float* w = (const float*)d_in[1];
    const float* b = (const float*)d_in[2];
    float* out = (float*)d_out;
    // split_num (d_in[3]) is a semantic no-op: K-slices sum to the full GEMM.

    if (ws_size >= WS_NEEDED) {
        unsigned short* wbf = (unsigned short*)d_ws;
        unsigned short* hbf = wbf + W_ELEMS;
        cvt_f32_bf16<<<2048, 256, 0, stream>>>(w, wbf, W_ELEMS / 8);
        cvt_f32_bf16<<<512, 256, 0, stream>>>(h, hbf, H_ELEMS / 8);
        lmhead_gemm_256<<<NWG, 512, 0, stream>>>(hbf, wbf, b, out);
    } else {
        lmhead_gemm_f32<<<4000, 256, 0, stream>>>(h, w, b, out);
    }
}